// Round 7
// baseline (700.973 us; speedup 1.0000x reference)
//
#include <hip/hip_runtime.h>

// DIAGNOSTIC ROUND: identical to R5 (best: 514 us) but stores everything 3x
// (asm memory fence between passes so DSE can't eliminate). Purpose: push our
// kernel's dur above the harness's 2.147 GB poison fills (~345 us) so rocprof
// top-5 finally shows OUR dispatch's FETCH_SIZE / WRITE_SIZE / hbm_gbps.
//   - If FETCH_SIZE ~= WRITE_SIZE: stores RFO-fetch output lines (explains the
//     stable 172 us = (512MiB W + 512MiB R)/6.25 TB/s plateau of R3/R5/R6).
//   - If FETCH_SIZE ~= 0 and hbm_gbps ~= 3.2 TB/s: store-pipe/pattern limit.

typedef float f32x4 __attribute__((ext_vector_type(4)));

constexpr int L   = 4096;
constexpr int NB  = 4;
constexpr int RPB = 16;                 // rows per block
constexpr int BPC = L / RPB;            // blocks per channel = 256

__global__ __launch_bounds__(256) void seq_embed(const f32x4* __restrict__ oh4,
                                                 float* __restrict__ out) {
    __shared__ float col[L];            // 16 KiB (bottom channels only)
    const int blk  = blockIdx.x;        // 0..2047
    const int c    = blk >> 8;          // channel 0..7
    const int row0 = (blk & (BPC - 1)) * RPB;
    const int t    = threadIdx.x;
    f32x4* __restrict__ out4 = reinterpret_cast<f32x4*>(out);

    if (c < NB) {
        const float* oh = reinterpret_cast<const float*>(oh4);
        float v[RPB];
#pragma unroll
        for (int r = 0; r < RPB; ++r) v[r] = oh[(row0 + r) * NB + c];
        for (int pass = 0; pass < 3; ++pass) {
#pragma unroll
            for (int r = 0; r < RPB; ++r) {
                f32x4* orow = out4 + (size_t)(c * L + row0 + r) * (L / 4);
                const f32x4 v4 = {v[r], v[r], v[r], v[r]};
#pragma unroll
                for (int k = 0; k < 4; ++k)
                    __builtin_nontemporal_store(v4, &orow[t + 256 * k]);
            }
            asm volatile("" ::: "memory");   // fence: keep all 3 passes
        }
    } else {
        const int cc = c - NB;
#pragma unroll
        for (int k = 0; k < 16; ++k) {
            const int p = t + 256 * k;
            const f32x4 w = oh4[p];          // coalesced 16 B/lane
            col[p] = w[cc];
        }
        __syncthreads();
        const f32x4* col4 = reinterpret_cast<const f32x4*>(col);
        f32x4 v[4];
#pragma unroll
        for (int k = 0; k < 4; ++k) v[k] = col4[t + 256 * k];  // 4 ds_read_b128
        for (int pass = 0; pass < 3; ++pass) {
#pragma unroll
            for (int r = 0; r < RPB; ++r) {
                f32x4* orow = out4 + (size_t)(c * L + row0 + r) * (L / 4);
#pragma unroll
                for (int k = 0; k < 4; ++k)
                    __builtin_nontemporal_store(v[k], &orow[t + 256 * k]);
            }
            asm volatile("" ::: "memory");   // fence: keep all 3 passes
        }
    }
}

extern "C" void kernel_launch(void* const* d_in, const int* in_sizes, int n_in,
                              void* d_out, int out_size, void* d_ws, size_t ws_size,
                              hipStream_t stream) {
    const f32x4* oh4 = (const f32x4*)d_in[0];
    float* out = (float*)d_out;
    seq_embed<<<8 * BPC, 256, 0, stream>>>(oh4, out);
}

// Round 8
// 514.039 us; speedup vs baseline: 1.3637x; 1.3637x over previous
//
#include <hip/hip_runtime.h>

// out[c,i,j] = one_hot[i,c]   (c<4)   — row broadcast
// out[c,i,j] = one_hot[j,c-4] (c>=4)  — column broadcast
// L=4096, one_hot [L,4] f32, out [8,L,L] f32 (512 MiB, pure write-BW bound).
//
// FINAL (R5 structure). Evidence trail:
//   R3: 2048 long-lived blocks, 64 f32x4 stores/thread from regs: 630->518 us.
//   R5: + nontemporal stores: 514 us.
//   R6: fill-style flat grid-stride sweep: 534 us (neutral-worse; reverted).
//   R7 diagnostic (3x store passes): +187 us for 2 extra 512 MiB passes
//       => marginal store BW = 536.9 MB / 93.5 us = 5.74 TB/s = 92% of the
//       rocclr fill ceiling (6.25 TB/s) on this harness. Kernel is ~95 us vs
//       86 us pure-write floor; the remaining ~420 us of dur_us is harness
//       fixed cost (2.147 GB poison fill ~346 us + restore/replay overhead).
//       => at the memory roofline; output bytes are irreducible.

typedef float f32x4 __attribute__((ext_vector_type(4)));

constexpr int L   = 4096;
constexpr int NB  = 4;
constexpr int RPB = 16;                 // rows per block
constexpr int BPC = L / RPB;            // blocks per channel = 256

__global__ __launch_bounds__(256) void seq_embed(const f32x4* __restrict__ oh4,
                                                 float* __restrict__ out) {
    __shared__ float col[L];            // 16 KiB (bottom channels only)
    const int blk  = blockIdx.x;        // 0..2047
    const int c    = blk >> 8;          // channel 0..7
    const int row0 = (blk & (BPC - 1)) * RPB;
    const int t    = threadIdx.x;
    f32x4* __restrict__ out4 = reinterpret_cast<f32x4*>(out);

    if (c < NB) {
        const float* oh = reinterpret_cast<const float*>(oh4);
        float v[RPB];
#pragma unroll
        for (int r = 0; r < RPB; ++r) v[r] = oh[(row0 + r) * NB + c];
#pragma unroll
        for (int r = 0; r < RPB; ++r) {
            f32x4* orow = out4 + (size_t)(c * L + row0 + r) * (L / 4);
            const f32x4 v4 = {v[r], v[r], v[r], v[r]};
#pragma unroll
            for (int k = 0; k < 4; ++k)
                __builtin_nontemporal_store(v4, &orow[t + 256 * k]);
        }
    } else {
        const int cc = c - NB;
        // stage column cc once per block with coalesced float4 loads
#pragma unroll
        for (int k = 0; k < 16; ++k) {
            const int p = t + 256 * k;
            const f32x4 w = oh4[p];              // 16 B/lane, lane-consecutive
            col[p] = w[cc];
        }
        __syncthreads();
        const f32x4* col4 = reinterpret_cast<const f32x4*>(col);
        f32x4 v[4];
#pragma unroll
        for (int k = 0; k < 4; ++k) v[k] = col4[t + 256 * k];  // 4 ds_read_b128
#pragma unroll
        for (int r = 0; r < RPB; ++r) {
            f32x4* orow = out4 + (size_t)(c * L + row0 + r) * (L / 4);
#pragma unroll
            for (int k = 0; k < 4; ++k)
                __builtin_nontemporal_store(v[k], &orow[t + 256 * k]);
        }
    }
}

extern "C" void kernel_launch(void* const* d_in, const int* in_sizes, int n_in,
                              void* d_out, int out_size, void* d_ws, size_t ws_size,
                              hipStream_t stream) {
    const f32x4* oh4 = (const f32x4*)d_in[0];
    float* out = (float*)d_out;
    seq_embed<<<8 * BPC, 256, 0, stream>>>(oh4, out);
}